// Round 6
// baseline (458.882 us; speedup 1.0000x reference)
//
#include <hip/hip_runtime.h>
#include <math.h>
#include <stdint.h>

#define S_LEN 1024
#define D_DIM 64
#define BH    32
#define KSHIFT 13
#define NBINS 130048u             // 0x3F800000 >> 13 : |score| < 1.0, 18-bit keys
#define HOT_LO 115712u            // (113<<23)>>13 : |s| >= 2^-14
#define NHOT   14336u             // NBINS - HOT_LO
#define NCHUNK 254                // NBINS / 512
#define HBLK   256                // hist kernel blocks
#define INV_NM1 (1.0f/33554431.0f)
#define INV_N   (2.9802322387695312e-08f)  // 1/2^25
#define FIX_TH  1e-4f             // |s| below this -> fp64 recompute (~21K elems)
#define FIX_CAP 262144u

typedef _Float16 half8 __attribute__((ext_vector_type(8)));
typedef float    floatx4 __attribute__((ext_vector_type(4)));

// ---------------- row norms: 1/(||row||+1e-5), fp64 + fp32 copies ----------------
__global__ __launch_bounds__(256) void norms_kernel(
    const float* __restrict__ Q, const float* __restrict__ K,
    double* __restrict__ qinvD, double* __restrict__ kinvD,
    float* __restrict__ qinvF, float* __restrict__ kinvF) {
  int row  = blockIdx.x * 4 + (threadIdx.x >> 6);
  int lane = threadIdx.x & 63;
  const float* src; double* dstD; float* dstF; int r = row;
  if (row < BH * S_LEN) { src = Q; dstD = qinvD; dstF = qinvF; }
  else                  { src = K; dstD = kinvD; dstF = kinvF; r = row - BH * S_LEN; }
  double v = (double)src[(size_t)r * D_DIM + lane];
  double s = v * v;
  #pragma unroll
  for (int off = 32; off; off >>= 1) s += __shfl_down(s, off);
  if (lane == 0) {
    double inv = 1.0 / (sqrt(s) + 1e-5);
    dstD[r] = inv;
    dstF[r] = (float)inv;
  }
}

// ---------------- QK^T fp32 -> score; flag tiny |s| for fp64 fixup ----------------
__global__ __launch_bounds__(256) void qk_kernel(
    const float* __restrict__ Q, const float* __restrict__ K,
    const float* __restrict__ qinvF, const float* __restrict__ kinvF,
    float* __restrict__ score, unsigned* __restrict__ list,
    unsigned* __restrict__ counter) {
  __shared__ float Qs[64][68];   // [k][i]
  __shared__ float Ks[64][68];   // [k][j]
  int bh = blockIdx.z;
  int i0 = blockIdx.y * 64;
  int j0 = blockIdx.x * 64;
  int tid = threadIdx.x;
  const float* Qb = Q + ((size_t)bh * S_LEN + i0) * D_DIM;
  const float* Kb = K + ((size_t)bh * S_LEN + j0) * D_DIM;
  #pragma unroll
  for (int l = 0; l < 4; ++l) {
    int idx4 = l * 256 + tid;
    int row  = idx4 >> 4;
    int c4   = idx4 & 15;
    float4 v = ((const float4*)Qb)[row * 16 + c4];
    Qs[c4*4+0][row] = v.x; Qs[c4*4+1][row] = v.y;
    Qs[c4*4+2][row] = v.z; Qs[c4*4+3][row] = v.w;
    float4 w = ((const float4*)Kb)[row * 16 + c4];
    Ks[c4*4+0][row] = w.x; Ks[c4*4+1][row] = w.y;
    Ks[c4*4+2][row] = w.z; Ks[c4*4+3][row] = w.w;
  }
  __syncthreads();
  int tx = tid & 15, ty = tid >> 4;
  float acc0[4][4] = {{0}}, acc1[4][4] = {{0}};
  #pragma unroll 8
  for (int k = 0; k < 64; k += 2) {
    float4 a0 = *(const float4*)&Qs[k  ][ty*4];
    float4 b0 = *(const float4*)&Ks[k  ][tx*4];
    float4 a1 = *(const float4*)&Qs[k+1][ty*4];
    float4 b1 = *(const float4*)&Ks[k+1][tx*4];
    float ar0[4]={a0.x,a0.y,a0.z,a0.w}, br0[4]={b0.x,b0.y,b0.z,b0.w};
    float ar1[4]={a1.x,a1.y,a1.z,a1.w}, br1[4]={b1.x,b1.y,b1.z,b1.w};
    #pragma unroll
    for (int r = 0; r < 4; ++r)
      #pragma unroll
      for (int c = 0; c < 4; ++c) {
        acc0[r][c] = fmaf(ar0[r], br0[c], acc0[r][c]);
        acc1[r][c] = fmaf(ar1[r], br1[c], acc1[r][c]);
      }
  }
  float qi[4], kj[4];
  #pragma unroll
  for (int r = 0; r < 4; ++r) qi[r] = qinvF[(size_t)bh * S_LEN + i0 + ty*4 + r];
  #pragma unroll
  for (int c = 0; c < 4; ++c) kj[c] = kinvF[(size_t)bh * S_LEN + j0 + tx*4 + c];
  #pragma unroll
  for (int r = 0; r < 4; ++r) {
    float4 st;
    float* sp = (float*)&st;
    #pragma unroll
    for (int c = 0; c < 4; ++c) {
      float s = (acc0[r][c] + acc1[r][c]) * qi[r] * kj[c];
      sp[c] = s;
      if (fabsf(s) < FIX_TH) {
        unsigned idx = atomicAdd(counter, 1u);
        if (idx < FIX_CAP)
          list[idx] = ((unsigned)bh << 20) | ((unsigned)(i0 + ty*4 + r) << 10)
                    | (unsigned)(j0 + tx*4 + c);
      }
    }
    *(float4*)(score + ((size_t)bh * S_LEN + i0 + ty*4 + r) * S_LEN + j0 + tx*4) = st;
  }
}

// ---------------- sparse fp64 recompute of flagged scores ----------------
__global__ __launch_bounds__(256) void fixup_kernel(
    const float* __restrict__ Q, const float* __restrict__ K,
    const double* __restrict__ qinvD, const double* __restrict__ kinvD,
    const unsigned* __restrict__ list, const unsigned* __restrict__ counter,
    float* __restrict__ score) {
  unsigned n = counter[0];
  if (n > FIX_CAP) n = FIX_CAP;
  int lane = threadIdx.x & 63;
  unsigned gw = (blockIdx.x * 256 + threadIdx.x) >> 6;
  unsigned nw = (gridDim.x * 256) >> 6;
  for (unsigned e = gw; e < n; e += nw) {
    unsigned code = list[e];
    unsigned bh = code >> 20, i = (code >> 10) & 1023u, j = code & 1023u;
    double qv = (double)Q[((size_t)bh * S_LEN + i) * D_DIM + lane];
    double kv = (double)K[((size_t)bh * S_LEN + j) * D_DIM + lane];
    double p = qv * kv;
    #pragma unroll
    for (int off = 32; off; off >>= 1) p += __shfl_down(p, off);
    if (lane == 0)
      score[((size_t)bh * S_LEN + i) * S_LEN + j] =
          (float)(p * qinvD[(size_t)bh * S_LEN + i] * kinvD[(size_t)bh * S_LEN + j]);
  }
}

// ---------------- histogram: LDS-privatized hot range + u16 partial flush ----------------
__global__ __launch_bounds__(512) void hist_kernel(
    const float* __restrict__ score, unsigned* __restrict__ hist,
    unsigned short* __restrict__ partial) {
  __shared__ unsigned lh[NHOT];
  int tid = threadIdx.x;
  for (unsigned i = tid; i < NHOT; i += 512) lh[i] = 0u;
  __syncthreads();
  const float4* p = (const float4*)score + (size_t)blockIdx.x * 32768;
  #pragma unroll 4
  for (int it = 0; it < 64; ++it) {
    float4 v = p[it * 512 + tid];
    float vv[4] = {v.x, v.y, v.z, v.w};
    #pragma unroll
    for (int c = 0; c < 4; ++c) {
      unsigned b = __float_as_uint(fabsf(vv[c])) >> KSHIFT;
      if (b >= NBINS) b = NBINS - 1u;
      if (b >= HOT_LO) atomicAdd(&lh[b - HOT_LO], 1u);
      else             atomicAdd(&hist[b], 1u);     // rare (~4e-4 of values)
    }
  }
  __syncthreads();
  unsigned short* dst = partial + (size_t)blockIdx.x * NHOT;
  for (unsigned i = tid; i < NHOT; i += 512) dst[i] = (unsigned short)lh[i];
}

// ---------------- reduce partial histograms into hist hot range ----------------
__global__ __launch_bounds__(256) void hreduce_kernel(
    const unsigned short* __restrict__ partial, unsigned* __restrict__ hist) {
  unsigned bin = blockIdx.x * 256 + threadIdx.x;
  unsigned s = 0;
  #pragma unroll 8
  for (int b = 0; b < HBLK; ++b) s += (unsigned)partial[(size_t)b * NHOT + bin];
  hist[HOT_LO + bin] = s;
}

// ---------------- V (fp32 [j][d]) -> Vt (fp16 [d][j]) ----------------
__global__ __launch_bounds__(256) void vt_kernel(
    const float* __restrict__ V, _Float16* __restrict__ Vt) {
  __shared__ _Float16 T[64][72];
  int bh = blockIdx.y, j0 = blockIdx.x * 64, tid = threadIdx.x;
  const float* Vb = V + ((size_t)bh * S_LEN + j0) * D_DIM;
  #pragma unroll
  for (int l = 0; l < 4; ++l) {
    int idx = l * 256 + tid;
    int jr = idx >> 4, d4 = idx & 15;
    float4 v = ((const float4*)Vb)[idx];
    T[d4*4+0][jr] = (_Float16)v.x;
    T[d4*4+1][jr] = (_Float16)v.y;
    T[d4*4+2][jr] = (_Float16)v.z;
    T[d4*4+3][jr] = (_Float16)v.w;
  }
  __syncthreads();
  _Float16* Ob = Vt + (size_t)bh * D_DIM * S_LEN + j0;
  #pragma unroll
  for (int l = 0; l < 2; ++l) {
    int idx = l * 256 + tid;
    int d = idx >> 3, jc = idx & 7;
    uint4 val = *(const uint4*)&T[d][jc*8];
    *(uint4*)(Ob + (size_t)d * S_LEN + jc*8) = val;
  }
}

// ---------------- histogram exclusive scan (3 stages), chunk=512 ----------------
__global__ __launch_bounds__(256) void scan1_kernel(const unsigned* __restrict__ hist,
                                                    unsigned* __restrict__ csum) {
  __shared__ unsigned sd[256];
  int c = blockIdx.x, t = threadIdx.x;
  const unsigned* p = hist + (size_t)c * 512;
  sd[t] = p[t] + p[t + 256];
  __syncthreads();
  for (int off = 128; off; off >>= 1) {
    if (t < off) sd[t] += sd[t + off];
    __syncthreads();
  }
  if (t == 0) csum[c] = sd[0];
}

__global__ __launch_bounds__(256) void scan2_kernel(unsigned* __restrict__ csum) {
  __shared__ unsigned d[256];
  int t = threadIdx.x;
  unsigned v = (t < NCHUNK) ? csum[t] : 0u;
  d[t] = v; __syncthreads();
  for (int off = 1; off < 256; off <<= 1) {
    unsigned x = (t >= off) ? d[t - off] : 0u;
    __syncthreads();
    d[t] += x;
    __syncthreads();
  }
  if (t < NCHUNK) csum[t] = d[t] - v;   // exclusive
}

// scan3: per-bin midrank -> tTab16[b] = fp16(-log(prob(midrank)))
__global__ __launch_bounds__(256) void scan3_kernel(const unsigned* __restrict__ hist,
                                                    const unsigned* __restrict__ csum,
                                                    _Float16* __restrict__ tTab16) {
  __shared__ unsigned ts[256];
  int c = blockIdx.x, t = threadIdx.x;
  const unsigned* p = hist + (size_t)c * 512 + t * 2;
  unsigned l0 = p[0], l1 = p[1];
  unsigned s = l0 + l1;
  ts[t] = s; __syncthreads();
  for (int off = 1; off < 256; off <<= 1) {
    unsigned x = (t >= off) ? ts[t - off] : 0u;
    __syncthreads();
    ts[t] += x;
    __syncthreads();
  }
  unsigned base = csum[c] + ts[t] - s;
  int idx = c * 512 + t * 2;
  float r0 = (float)base + 0.5f * ((float)l0 - 1.0f);
  tTab16[idx]     = (_Float16)(-__logf(fmaf(r0, INV_NM1, INV_N)));
  float r1 = (float)(base + l0) + 0.5f * ((float)l1 - 1.0f);
  tTab16[idx + 1] = (_Float16)(-__logf(fmaf(r1, INV_NM1, INV_N)));
}

// ---------------- fused map + MFMA P.V + rowsum-normalized epilogue ----------------
__global__ __launch_bounds__(256) void pv_mfma_kernel(
    const float* __restrict__ score, const _Float16* __restrict__ Vt,
    const unsigned short* __restrict__ tTab16, float* __restrict__ out) {
  __shared__ unsigned short ldsT[NHOT];
  int tid = threadIdx.x;
  {
    const unsigned* gsrc = (const unsigned*)(tTab16 + HOT_LO);
    unsigned* ldst = (unsigned*)ldsT;
    #pragma unroll
    for (int i = 0; i < 28; ++i)
      ldst[i * 256 + tid] = gsrc[i * 256 + tid];
  }
  __syncthreads();

  int bh   = blockIdx.y;
  int wave = tid >> 6;
  int lane = tid & 63;
  int m    = lane & 15;
  int quad = lane >> 4;
  int i0   = blockIdx.x * 64 + wave * 16;
  const float*    Sb = score + ((size_t)bh * S_LEN + i0 + m) * S_LEN;
  const _Float16* Vb = Vt + (size_t)bh * D_DIM * S_LEN;
  floatx4 acc[4];
  #pragma unroll
  for (int n = 0; n < 4; ++n) acc[n] = (floatx4){0.f, 0.f, 0.f, 0.f};
  float rsum = 0.f;

  for (int ks = 0; ks < 32; ++ks) {
    int k0 = ks * 32 + quad * 8;
    float4 s0 = *(const float4*)(Sb + k0);
    float4 s1 = *(const float4*)(Sb + k0 + 4);
    float sv[8] = {s0.x, s0.y, s0.z, s0.w, s1.x, s1.y, s1.z, s1.w};
    union { unsigned short u[8]; half8 h; } af;
    #pragma unroll
    for (int e = 0; e < 8; ++e) {
      unsigned u = __float_as_uint(sv[e]);
      unsigned a = u & 0x7fffffffu;
      unsigned b = a >> KSHIFT;
      if (b > NBINS - 1u) b = NBINS - 1u;
      unsigned short tb;
      if (b >= HOT_LO) tb = ldsT[b - HOT_LO];
      else             tb = tTab16[b];
      if (a == 0u) tb = 0;
      af.u[e] = (unsigned short)(tb ^ ((u >> 16) & 0x8000u));
      unsigned short tabs = (unsigned short)(tb & 0x7fffu);
      _Float16 th = __builtin_bit_cast(_Float16, tabs);
      rsum += (float)th;
    }
    half8 bf[4];
    #pragma unroll
    for (int n = 0; n < 4; ++n)
      bf[n] = *(const half8*)(Vb + (size_t)(n * 16 + m) * S_LEN + k0);
    #pragma unroll
    for (int n = 0; n < 4; ++n)
      acc[n] = __builtin_amdgcn_mfma_f32_16x16x32_f16(af.h, bf[n], acc[n], 0, 0, 0);
  }

  rsum += __shfl_xor(rsum, 16);
  rsum += __shfl_xor(rsum, 32);
  float inv = 1.0f / rsum;
  #pragma unroll
  for (int r = 0; r < 4; ++r) {
    int row = quad * 4 + r;
    float invr = __shfl(inv, row);
    float* op = out + ((size_t)bh * S_LEN + i0 + row) * D_DIM + m;
    #pragma unroll
    for (int n = 0; n < 4; ++n)
      op[n * 16] = acc[n][r] * invr;
  }
}

// ---------------- launch ----------------
extern "C" void kernel_launch(void* const* d_in, const int* in_sizes, int n_in,
                              void* d_out, int out_size, void* d_ws, size_t ws_size,
                              hipStream_t stream) {
  const float* Q = (const float*)d_in[0];
  const float* K = (const float*)d_in[1];
  const float* V = (const float*)d_in[2];
  float* out = (float*)d_out;
  char* ws = (char*)d_ws;
  // Layout (max 142,077,952 B == round-5-proven footprint):
  //   score [0, 134217728) ; hist [134217728, 134737920)
  //   P = 134737920 .. 142077952 : partial (256*14336 u16), live hist->hreduce.
  //   Aliased into P (disjoint lifetimes, all dead before/after partial's):
  //     csum   P+0        (1016 B, scan1->scan3)
  //     tTab16 P+1024     (260096 B, scan3->pv)
  //     Vt     P+262144   (4 MB, vt->pv; vt runs after hreduce)
  //     qinvD  P+4456448, kinvD P+4718592 (256 KB each, norms->fixup)
  //     qinvF  P+4980736, kinvF P+5111808 (128 KB each, norms->qk)
  //     list   P+5242880  (1 MB, qk->fixup)
  //     counter P+6291456 (4 B, qk->fixup)
  float*          score   = (float*)(ws);
  unsigned*       hist    = (unsigned*)(ws + 134217728);
  unsigned short* partial = (unsigned short*)(ws + 134737920);
  unsigned*       csum    = (unsigned*)(ws + 134737920);
  _Float16*       tTab16  = (_Float16*)(ws + 134738944);
  _Float16*       Vt      = (_Float16*)(ws + 135000064);
  double*         qinvD   = (double*)(ws + 139194368);
  double*         kinvD   = (double*)(ws + 139456512);
  float*          qinvF   = (float*)(ws + 139718656);
  float*          kinvF   = (float*)(ws + 139849728);
  unsigned*       list    = (unsigned*)(ws + 139980800);
  unsigned*       counter = (unsigned*)(ws + 141029376);

  hipMemsetAsync(hist, 0, NBINS * sizeof(unsigned), stream);
  hipMemsetAsync(counter, 0, sizeof(unsigned), stream);
  norms_kernel<<<(2 * BH * S_LEN) / 4, 256, 0, stream>>>(Q, K, qinvD, kinvD, qinvF, kinvF);
  qk_kernel<<<dim3(16, 16, BH), 256, 0, stream>>>(Q, K, qinvF, kinvF, score, list, counter);
  fixup_kernel<<<256, 256, 0, stream>>>(Q, K, qinvD, kinvD, list, counter, score);
  hist_kernel<<<HBLK, 512, 0, stream>>>(score, hist, partial);
  hreduce_kernel<<<NHOT / 256, 256, 0, stream>>>(partial, hist);
  vt_kernel<<<dim3(16, BH), 256, 0, stream>>>(V, Vt);
  scan1_kernel<<<NCHUNK, 256, 0, stream>>>(hist, csum);
  scan2_kernel<<<1, 256, 0, stream>>>(csum);
  scan3_kernel<<<NCHUNK, 256, 0, stream>>>(hist, csum, tTab16);
  pv_mfma_kernel<<<dim3(16, BH), 256, 0, stream>>>(
      score, Vt, (const unsigned short*)tTab16, out);
}

// Round 7
// 238.552 us; speedup vs baseline: 1.9236x; 1.9236x over previous
//
#include <hip/hip_runtime.h>
#include <math.h>
#include <stdint.h>

#define S_LEN 1024
#define D_DIM 64
#define BH    32
#define KSHIFT 13
#define NBINS 130048u             // 0x3F800000 >> 13 : |score| < 1.0, 18-bit keys
#define HOT_LO 115712u            // (113<<23)>>13 : |s| >= 2^-14
#define NHOT   14336u             // NBINS - HOT_LO
#define NCHUNK 254                // NBINS / 512
#define HBLK   256                // hist kernel blocks
#define INV_NM1 (1.0f/33554431.0f)
#define INV_N   (2.9802322387695312e-08f)  // 1/2^25
#define FIX_TH  1e-4f             // |s| below this -> wave-coop fp64 recompute (~21K elems)

typedef _Float16 half8 __attribute__((ext_vector_type(8)));
typedef short    short8 __attribute__((ext_vector_type(8)));
typedef float    floatx4 __attribute__((ext_vector_type(4)));

// ---------------- row norms: 1/(||row||+1e-5), fp64 + fp32 copies ----------------
__global__ __launch_bounds__(256) void norms_kernel(
    const float* __restrict__ Q, const float* __restrict__ K,
    double* __restrict__ qinvD, double* __restrict__ kinvD,
    float* __restrict__ qinvF, float* __restrict__ kinvF) {
  int row  = blockIdx.x * 4 + (threadIdx.x >> 6);
  int lane = threadIdx.x & 63;
  const float* src; double* dstD; float* dstF; int r = row;
  if (row < BH * S_LEN) { src = Q; dstD = qinvD; dstF = qinvF; }
  else                  { src = K; dstD = kinvD; dstF = kinvF; r = row - BH * S_LEN; }
  double v = (double)src[(size_t)r * D_DIM + lane];
  double s = v * v;
  #pragma unroll
  for (int off = 32; off; off >>= 1) s += __shfl_down(s, off);
  if (lane == 0) {
    double inv = 1.0 / (sqrt(s) + 1e-5);
    dstD[r] = inv;
    dstF[r] = (float)inv;
  }
}

// bf16 split helper: x -> hi (RNE) + lo (RZ of residual), as raw bf16 bit patterns
__device__ __forceinline__ void bf16_split(float x, short& hi, short& lo) {
  unsigned u = __float_as_uint(x);
  unsigned h = (u + 0x7FFFu + ((u >> 16) & 1u)) >> 16;   // RNE to bf16
  float hf = __uint_as_float(h << 16);
  float lf = x - hf;                                     // exact (Sterbenz)
  hi = (short)h;
  lo = (short)(__float_as_uint(lf) >> 16);               // RZ to bf16
}

// ---------------- QK^T via bf16-split MFMA (hi*hi + hi*lo + lo*hi) ----------------
__global__ __launch_bounds__(256) void qk_mfma_kernel(
    const float* __restrict__ Q, const float* __restrict__ K,
    const float* __restrict__ qinvF, const float* __restrict__ kinvF,
    float* __restrict__ score) {
  __shared__ short Qhi[64][72], Qlo[64][72];   // stride 72 shorts = 144 B: 16B-aligned, 2-way banks
  __shared__ short Khi[64][72], Klo[64][72];
  int bh = blockIdx.z;
  int i0 = blockIdx.y * 64;
  int j0 = blockIdx.x * 64;
  int tid = threadIdx.x;
  const float* Qb = Q + ((size_t)bh * S_LEN + i0) * D_DIM;
  const float* Kb = K + ((size_t)bh * S_LEN + j0) * D_DIM;
  #pragma unroll
  for (int l = 0; l < 4; ++l) {
    int idx4 = l * 256 + tid;          // 0..1023 float4 of 64x64 tile
    int row  = idx4 >> 4;
    int c4   = idx4 & 15;
    float qi = qinvF[(size_t)bh * S_LEN + i0 + row];
    float4 v = ((const float4*)Qb)[idx4];
    float qv[4] = {v.x * qi, v.y * qi, v.z * qi, v.w * qi};
    short qh[4], ql[4];
    #pragma unroll
    for (int c = 0; c < 4; ++c) bf16_split(qv[c], qh[c], ql[c]);
    *(short4*)&Qhi[row][c4 * 4] = make_short4(qh[0], qh[1], qh[2], qh[3]);
    *(short4*)&Qlo[row][c4 * 4] = make_short4(ql[0], ql[1], ql[2], ql[3]);
    float kj = kinvF[(size_t)bh * S_LEN + j0 + row];
    float4 w = ((const float4*)Kb)[idx4];
    float kv[4] = {w.x * kj, w.y * kj, w.z * kj, w.w * kj};
    short kh[4], kl[4];
    #pragma unroll
    for (int c = 0; c < 4; ++c) bf16_split(kv[c], kh[c], kl[c]);
    *(short4*)&Khi[row][c4 * 4] = make_short4(kh[0], kh[1], kh[2], kh[3]);
    *(short4*)&Klo[row][c4 * 4] = make_short4(kl[0], kl[1], kl[2], kl[3]);
  }
  __syncthreads();
  int wave = tid >> 6;
  int lane = tid & 63;
  int m    = lane & 15;
  int quad = lane >> 4;
  floatx4 acc[4];
  #pragma unroll
  for (int n = 0; n < 4; ++n) acc[n] = (floatx4){0.f, 0.f, 0.f, 0.f};
  #pragma unroll
  for (int ks = 0; ks < 2; ++ks) {
    int kb = ks * 32 + quad * 8;
    short8 a_hi = *(const short8*)&Qhi[wave * 16 + m][kb];
    short8 a_lo = *(const short8*)&Qlo[wave * 16 + m][kb];
    #pragma unroll
    for (int nt = 0; nt < 4; ++nt) {
      short8 b_hi = *(const short8*)&Khi[nt * 16 + m][kb];
      short8 b_lo = *(const short8*)&Klo[nt * 16 + m][kb];
      acc[nt] = __builtin_amdgcn_mfma_f32_16x16x32_bf16(a_hi, b_hi, acc[nt], 0, 0, 0);
      acc[nt] = __builtin_amdgcn_mfma_f32_16x16x32_bf16(a_hi, b_lo, acc[nt], 0, 0, 0);
      acc[nt] = __builtin_amdgcn_mfma_f32_16x16x32_bf16(a_lo, b_hi, acc[nt], 0, 0, 0);
    }
  }
  // C/D: row = quad*4 + r, col = lane&15
  #pragma unroll
  for (int r = 0; r < 4; ++r) {
    float* op = score + ((size_t)bh * S_LEN + i0 + wave * 16 + quad * 4 + r) * S_LEN + j0 + m;
    #pragma unroll
    for (int nt = 0; nt < 4; ++nt)
      op[nt * 16] = acc[nt][r];
  }
}

// ------- histogram (LDS hot range) + fused wave-coop fp64 fixup of tiny scores -------
__global__ __launch_bounds__(512) void hist_kernel(
    float* __restrict__ score, const float* __restrict__ Q, const float* __restrict__ K,
    const double* __restrict__ qinvD, const double* __restrict__ kinvD,
    unsigned* __restrict__ hist, unsigned char* __restrict__ partial) {
  __shared__ unsigned lh[NHOT];
  int tid = threadIdx.x;
  int lane = tid & 63;
  for (unsigned i = tid; i < NHOT; i += 512) lh[i] = 0u;
  __syncthreads();
  const float4* p = (const float4*)score + (size_t)blockIdx.x * 32768;
  for (int it = 0; it < 64; ++it) {
    float4 v = p[it * 512 + tid];
    float vv[4] = {v.x, v.y, v.z, v.w};
    // ---- rare fp64 fixup (wave-cooperative, no global atomics) ----
    bool anyf = (fabsf(vv[0]) < FIX_TH) | (fabsf(vv[1]) < FIX_TH) |
                (fabsf(vv[2]) < FIX_TH) | (fabsf(vv[3]) < FIX_TH);
    unsigned long long am = __ballot(anyf);
    while (am) {
      int src = (int)(__ffsll((long long)am) - 1);
      am &= am - 1;
      unsigned base4 = (unsigned)(blockIdx.x * 32768u + (unsigned)(it * 512 + tid));
      unsigned b4 = __shfl(base4, src);
      #pragma unroll
      for (int c = 0; c < 4; ++c) {
        float sc = __shfl(vv[c], src);
        if (fabsf(sc) < FIX_TH) {
          unsigned flat = b4 * 4u + (unsigned)c;
          unsigned bh = flat >> 20, i = (flat >> 10) & 1023u, j = flat & 1023u;
          double qd = (double)Q[((size_t)bh * S_LEN + i) * D_DIM + lane];
          double kd = (double)K[((size_t)bh * S_LEN + j) * D_DIM + lane];
          double pd = qd * kd;
          #pragma unroll
          for (int off = 32; off; off >>= 1) pd += __shfl_down(pd, off);
          float corr = 0.f;
          if (lane == 0)
            corr = (float)(pd * qinvD[(size_t)bh * S_LEN + i] * kinvD[(size_t)bh * S_LEN + j]);
          corr = __shfl(corr, 0);
          if (lane == src) {
            vv[c] = corr;
            score[(size_t)flat] = corr;
          }
        }
      }
    }
    // ---- binning ----
    #pragma unroll
    for (int c = 0; c < 4; ++c) {
      unsigned b = __float_as_uint(fabsf(vv[c])) >> KSHIFT;
      if (b >= NBINS) b = NBINS - 1u;
      if (b >= HOT_LO) atomicAdd(&lh[b - HOT_LO], 1u);
      else             atomicAdd(&hist[b], 1u);     // rare cold bins
    }
  }
  __syncthreads();
  unsigned char* dst = partial + (size_t)blockIdx.x * NHOT;
  for (unsigned i = tid; i < NHOT; i += 512) dst[i] = (unsigned char)lh[i];
}

// ---------------- reduce u8 partial histograms into hist hot range ----------------
__global__ __launch_bounds__(256) void hreduce_kernel(
    const unsigned char* __restrict__ partial, unsigned* __restrict__ hist) {
  unsigned bin = blockIdx.x * 256 + threadIdx.x;
  unsigned s = 0;
  #pragma unroll 8
  for (int b = 0; b < HBLK; ++b) s += (unsigned)partial[(size_t)b * NHOT + bin];
  hist[HOT_LO + bin] = s;
}

// ---------------- V (fp32 [j][d]) -> Vt (fp16 [d][j]) ----------------
__global__ __launch_bounds__(256) void vt_kernel(
    const float* __restrict__ V, _Float16* __restrict__ Vt) {
  __shared__ _Float16 T[64][72];
  int bh = blockIdx.y, j0 = blockIdx.x * 64, tid = threadIdx.x;
  const float* Vb = V + ((size_t)bh * S_LEN + j0) * D_DIM;
  #pragma unroll
  for (int l = 0; l < 4; ++l) {
    int idx = l * 256 + tid;
    int jr = idx >> 4, d4 = idx & 15;
    float4 v = ((const float4*)Vb)[idx];
    T[d4*4+0][jr] = (_Float16)v.x;
    T[d4*4+1][jr] = (_Float16)v.y;
    T[d4*4+2][jr] = (_Float16)v.z;
    T[d4*4+3][jr] = (_Float16)v.w;
  }
  __syncthreads();
  _Float16* Ob = Vt + (size_t)bh * D_DIM * S_LEN + j0;
  #pragma unroll
  for (int l = 0; l < 2; ++l) {
    int idx = l * 256 + tid;
    int d = idx >> 3, jc = idx & 7;
    uint4 val = *(const uint4*)&T[d][jc*8];
    *(uint4*)(Ob + (size_t)d * S_LEN + jc*8) = val;
  }
}

// ---------------- histogram exclusive scan (3 stages), chunk=512 ----------------
__global__ __launch_bounds__(256) void scan1_kernel(const unsigned* __restrict__ hist,
                                                    unsigned* __restrict__ csum) {
  __shared__ unsigned sd[256];
  int c = blockIdx.x, t = threadIdx.x;
  const unsigned* p = hist + (size_t)c * 512;
  sd[t] = p[t] + p[t + 256];
  __syncthreads();
  for (int off = 128; off; off >>= 1) {
    if (t < off) sd[t] += sd[t + off];
    __syncthreads();
  }
  if (t == 0) csum[c] = sd[0];
}

__global__ __launch_bounds__(256) void scan2_kernel(unsigned* __restrict__ csum) {
  __shared__ unsigned d[256];
  int t = threadIdx.x;
  unsigned v = (t < NCHUNK) ? csum[t] : 0u;
  d[t] = v; __syncthreads();
  for (int off = 1; off < 256; off <<= 1) {
    unsigned x = (t >= off) ? d[t - off] : 0u;
    __syncthreads();
    d[t] += x;
    __syncthreads();
  }
  if (t < NCHUNK) csum[t] = d[t] - v;   // exclusive
}

// scan3: per-bin midrank -> tTab16[b] = fp16(-log(prob(midrank)))
__global__ __launch_bounds__(256) void scan3_kernel(const unsigned* __restrict__ hist,
                                                    const unsigned* __restrict__ csum,
                                                    _Float16* __restrict__ tTab16) {
  __shared__ unsigned ts[256];
  int c = blockIdx.x, t = threadIdx.x;
  const unsigned* p = hist + (size_t)c * 512 + t * 2;
  unsigned l0 = p[0], l1 = p[1];
  unsigned s = l0 + l1;
  ts[t] = s; __syncthreads();
  for (int off = 1; off < 256; off <<= 1) {
    unsigned x = (t >= off) ? ts[t - off] : 0u;
    __syncthreads();
    ts[t] += x;
    __syncthreads();
  }
  unsigned base = csum[c] + ts[t] - s;
  int idx = c * 512 + t * 2;
  float r0 = (float)base + 0.5f * ((float)l0 - 1.0f);
  tTab16[idx]     = (_Float16)(-__logf(fmaf(r0, INV_NM1, INV_N)));
  float r1 = (float)(base + l0) + 0.5f * ((float)l1 - 1.0f);
  tTab16[idx + 1] = (_Float16)(-__logf(fmaf(r1, INV_NM1, INV_N)));
}

// ---------------- fused map + MFMA P.V + rowsum-normalized epilogue ----------------
__global__ __launch_bounds__(256) void pv_mfma_kernel(
    const float* __restrict__ score, const _Float16* __restrict__ Vt,
    const unsigned short* __restrict__ tTab16, float* __restrict__ out) {
  __shared__ unsigned short ldsT[NHOT];
  int tid = threadIdx.x;
  {
    const unsigned* gsrc = (const unsigned*)(tTab16 + HOT_LO);
    unsigned* ldst = (unsigned*)ldsT;
    #pragma unroll
    for (int i = 0; i < 28; ++i)
      ldst[i * 256 + tid] = gsrc[i * 256 + tid];
  }
  __syncthreads();

  int bh   = blockIdx.y;
  int wave = tid >> 6;
  int lane = tid & 63;
  int m    = lane & 15;
  int quad = lane >> 4;
  int i0   = blockIdx.x * 64 + wave * 16;
  const float*    Sb = score + ((size_t)bh * S_LEN + i0 + m) * S_LEN;
  const _Float16* Vb = Vt + (size_t)bh * D_DIM * S_LEN;
  floatx4 acc[4];
  #pragma unroll
  for (int n = 0; n < 4; ++n) acc[n] = (floatx4){0.f, 0.f, 0.f, 0.f};
  float rsum = 0.f;

  for (int ks = 0; ks < 32; ++ks) {
    int k0 = ks * 32 + quad * 8;
    float4 s0 = *(const float4*)(Sb + k0);
    float4 s1 = *(const float4*)(Sb + k0 + 4);
    float sv[8] = {s0.x, s0.y, s0.z, s0.w, s1.x, s1.y, s1.z, s1.w};
    union { unsigned short u[8]; half8 h; } af;
    #pragma unroll
    for (int e = 0; e < 8; ++e) {
      unsigned u = __float_as_uint(sv[e]);
      unsigned a = u & 0x7fffffffu;
      unsigned b = a >> KSHIFT;
      if (b > NBINS - 1u) b = NBINS - 1u;
      unsigned short tb;
      if (b >= HOT_LO) tb = ldsT[b - HOT_LO];
      else             tb = tTab16[b];
      if (a == 0u) tb = 0;
      af.u[e] = (unsigned short)(tb ^ ((u >> 16) & 0x8000u));
      unsigned short tabs = (unsigned short)(tb & 0x7fffu);
      _Float16 th = __builtin_bit_cast(_Float16, tabs);
      rsum += (float)th;
    }
    half8 bf[4];
    #pragma unroll
    for (int n = 0; n < 4; ++n)
      bf[n] = *(const half8*)(Vb + (size_t)(n * 16 + m) * S_LEN + k0);
    #pragma unroll
    for (int n = 0; n < 4; ++n)
      acc[n] = __builtin_amdgcn_mfma_f32_16x16x32_f16(af.h, bf[n], acc[n], 0, 0, 0);
  }

  rsum += __shfl_xor(rsum, 16);
  rsum += __shfl_xor(rsum, 32);
  float inv = 1.0f / rsum;
  #pragma unroll
  for (int r = 0; r < 4; ++r) {
    int row = quad * 4 + r;
    float invr = __shfl(inv, row);
    float* op = out + ((size_t)bh * S_LEN + i0 + row) * D_DIM + m;
    #pragma unroll
    for (int n = 0; n < 4; ++n)
      op[n * 16] = acc[n][r] * invr;
  }
}

// ---------------- launch ----------------
extern "C" void kernel_launch(void* const* d_in, const int* in_sizes, int n_in,
                              void* d_out, int out_size, void* d_ws, size_t ws_size,
                              hipStream_t stream) {
  const float* Q = (const float*)d_in[0];
  const float* K = (const float*)d_in[1];
  const float* V = (const float*)d_in[2];
  float* out = (float*)d_out;
  char* ws = (char*)d_ws;
  // Layout (max byte used 139,455,488 < round-6-proven 142,077,952):
  //   score [0, 134217728) ; hist [134217728, 134737920)
  //   P = 134737920:
  //     partial u8 P+0 .. P+3670016            (live hist->hreduce)
  //     qinvD P+3670016, kinvD P+3932160       (256 KB each, live norms->hist)
  //     qinvF P+4194304, kinvF P+4325376       (128 KB each, live norms->qk)
  //     Vt    P+0 .. P+4194304                 (live vt->pv; aliases partial+qinvD/kinvD, all dead)
  //     csum  P+4456448 (1016 B, scan1->scan3)
  //     tTab16 P+4457472 (260096 B, scan3->pv)
  float*         score   = (float*)(ws);
  unsigned*      hist    = (unsigned*)(ws + 134217728);
  unsigned char* partial = (unsigned char*)(ws + 134737920);
  double*        qinvD   = (double*)(ws + 138407936);
  double*        kinvD   = (double*)(ws + 138670080);
  float*         qinvF   = (float*)(ws + 138932224);
  float*         kinvF   = (float*)(ws + 139063296);
  _Float16*      Vt      = (_Float16*)(ws + 134737920);
  unsigned*      csum    = (unsigned*)(ws + 139194368);
  _Float16*      tTab16  = (_Float16*)(ws + 139195392);

  hipMemsetAsync(hist, 0, NBINS * sizeof(unsigned), stream);
  norms_kernel<<<(2 * BH * S_LEN) / 4, 256, 0, stream>>>(Q, K, qinvD, kinvD, qinvF, kinvF);
  qk_mfma_kernel<<<dim3(16, 16, BH), 256, 0, stream>>>(Q, K, qinvF, kinvF, score);
  hist_kernel<<<HBLK, 512, 0, stream>>>(score, Q, K, qinvD, kinvD, hist, partial);
  hreduce_kernel<<<NHOT / 256, 256, 0, stream>>>(partial, hist);
  vt_kernel<<<dim3(16, BH), 256, 0, stream>>>(V, Vt);
  scan1_kernel<<<NCHUNK, 256, 0, stream>>>(hist, csum);
  scan2_kernel<<<1, 256, 0, stream>>>(csum);
  scan3_kernel<<<NCHUNK, 256, 0, stream>>>(hist, csum, tTab16);
  pv_mfma_kernel<<<dim3(16, BH), 256, 0, stream>>>(
      score, Vt, (const unsigned short*)tTab16, out);
}

// Round 8
// 218.028 us; speedup vs baseline: 2.1047x; 1.0941x over previous
//
#include <hip/hip_runtime.h>
#include <math.h>
#include <stdint.h>

#define S_LEN 1024
#define D_DIM 64
#define BH    32
#define KSHIFT 13
#define NBINS 130048u             // 0x3F800000 >> 13 : |score| < 1.0, 18-bit keys
#define HOT_LO 115712u            // pv LDS table: |s| >= 2^-14
#define NHOT   14336u             // pv table bins
#define HIST_LO 117760u           // hist LDS range: |s| >= 2^-12  ((115+12)? no: exp field 115 -> (115<<10))
#define NHOT_H  12288u            // NBINS - HIST_LO
#define NCHUNK 254                // NBINS / 512
#define HBLK   256                // hist kernel blocks (1024 thr each)
#define INV_NM1 (1.0f/33554431.0f)
#define INV_N   (2.9802322387695312e-08f)  // 1/2^25
#define FIX_TH  1e-4f             // |s| below this -> wave-coop fp64 recompute (~21K elems)

typedef _Float16 half8 __attribute__((ext_vector_type(8)));
typedef short    short8 __attribute__((ext_vector_type(8)));
typedef float    floatx4 __attribute__((ext_vector_type(4)));

// ---------------- row norms: 1/(||row||+1e-5), fp64 + fp32 copies ----------------
__global__ __launch_bounds__(256) void norms_kernel(
    const float* __restrict__ Q, const float* __restrict__ K,
    double* __restrict__ qinvD, double* __restrict__ kinvD,
    float* __restrict__ qinvF, float* __restrict__ kinvF) {
  int row  = blockIdx.x * 4 + (threadIdx.x >> 6);
  int lane = threadIdx.x & 63;
  const float* src; double* dstD; float* dstF; int r = row;
  if (row < BH * S_LEN) { src = Q; dstD = qinvD; dstF = qinvF; }
  else                  { src = K; dstD = kinvD; dstF = kinvF; r = row - BH * S_LEN; }
  double v = (double)src[(size_t)r * D_DIM + lane];
  double s = v * v;
  #pragma unroll
  for (int off = 32; off; off >>= 1) s += __shfl_down(s, off);
  if (lane == 0) {
    double inv = 1.0 / (sqrt(s) + 1e-5);
    dstD[r] = inv;
    dstF[r] = (float)inv;
  }
}

// bf16 split helper: x -> hi (RNE) + lo (RZ of residual), as raw bf16 bit patterns
__device__ __forceinline__ void bf16_split(float x, short& hi, short& lo) {
  unsigned u = __float_as_uint(x);
  unsigned h = (u + 0x7FFFu + ((u >> 16) & 1u)) >> 16;   // RNE to bf16
  float hf = __uint_as_float(h << 16);
  float lf = x - hf;                                     // exact (Sterbenz)
  hi = (short)h;
  lo = (short)(__float_as_uint(lf) >> 16);               // RZ to bf16
}

// ---------------- QK^T via bf16-split MFMA (hi*hi + hi*lo + lo*hi) ----------------
__global__ __launch_bounds__(256) void qk_mfma_kernel(
    const float* __restrict__ Q, const float* __restrict__ K,
    const float* __restrict__ qinvF, const float* __restrict__ kinvF,
    float* __restrict__ score) {
  __shared__ short Qhi[64][72], Qlo[64][72];   // stride 72 shorts = 144 B: 16B-aligned, 2-way banks
  __shared__ short Khi[64][72], Klo[64][72];
  int bh = blockIdx.z;
  int i0 = blockIdx.y * 64;
  int j0 = blockIdx.x * 64;
  int tid = threadIdx.x;
  const float* Qb = Q + ((size_t)bh * S_LEN + i0) * D_DIM;
  const float* Kb = K + ((size_t)bh * S_LEN + j0) * D_DIM;
  #pragma unroll
  for (int l = 0; l < 4; ++l) {
    int idx4 = l * 256 + tid;          // 0..1023 float4 of 64x64 tile
    int row  = idx4 >> 4;
    int c4   = idx4 & 15;
    float qi = qinvF[(size_t)bh * S_LEN + i0 + row];
    float4 v = ((const float4*)Qb)[idx4];
    float qv[4] = {v.x * qi, v.y * qi, v.z * qi, v.w * qi};
    short qh[4], ql[4];
    #pragma unroll
    for (int c = 0; c < 4; ++c) bf16_split(qv[c], qh[c], ql[c]);
    *(short4*)&Qhi[row][c4 * 4] = make_short4(qh[0], qh[1], qh[2], qh[3]);
    *(short4*)&Qlo[row][c4 * 4] = make_short4(ql[0], ql[1], ql[2], ql[3]);
    float kj = kinvF[(size_t)bh * S_LEN + j0 + row];
    float4 w = ((const float4*)Kb)[idx4];
    float kv[4] = {w.x * kj, w.y * kj, w.z * kj, w.w * kj};
    short kh[4], kl[4];
    #pragma unroll
    for (int c = 0; c < 4; ++c) bf16_split(kv[c], kh[c], kl[c]);
    *(short4*)&Khi[row][c4 * 4] = make_short4(kh[0], kh[1], kh[2], kh[3]);
    *(short4*)&Klo[row][c4 * 4] = make_short4(kl[0], kl[1], kl[2], kl[3]);
  }
  __syncthreads();
  int wave = tid >> 6;
  int lane = tid & 63;
  int m    = lane & 15;
  int quad = lane >> 4;
  floatx4 acc[4];
  #pragma unroll
  for (int n = 0; n < 4; ++n) acc[n] = (floatx4){0.f, 0.f, 0.f, 0.f};
  #pragma unroll
  for (int ks = 0; ks < 2; ++ks) {
    int kb = ks * 32 + quad * 8;
    short8 a_hi = *(const short8*)&Qhi[wave * 16 + m][kb];
    short8 a_lo = *(const short8*)&Qlo[wave * 16 + m][kb];
    #pragma unroll
    for (int nt = 0; nt < 4; ++nt) {
      short8 b_hi = *(const short8*)&Khi[nt * 16 + m][kb];
      short8 b_lo = *(const short8*)&Klo[nt * 16 + m][kb];
      acc[nt] = __builtin_amdgcn_mfma_f32_16x16x32_bf16(a_hi, b_hi, acc[nt], 0, 0, 0);
      acc[nt] = __builtin_amdgcn_mfma_f32_16x16x32_bf16(a_hi, b_lo, acc[nt], 0, 0, 0);
      acc[nt] = __builtin_amdgcn_mfma_f32_16x16x32_bf16(a_lo, b_hi, acc[nt], 0, 0, 0);
    }
  }
  // C/D: row = quad*4 + r, col = lane&15
  #pragma unroll
  for (int r = 0; r < 4; ++r) {
    float* op = score + ((size_t)bh * S_LEN + i0 + wave * 16 + quad * 4 + r) * S_LEN + j0 + m;
    #pragma unroll
    for (int nt = 0; nt < 4; ++nt)
      op[nt * 16] = acc[nt][r];
  }
}

// ------- histogram (LDS hot range, 1024thr/2 blocks-per-CU) + fused fp64 fixup -------
__global__ __launch_bounds__(1024) void hist_kernel(
    float* __restrict__ score, const float* __restrict__ Q, const float* __restrict__ K,
    const double* __restrict__ qinvD, const double* __restrict__ kinvD,
    unsigned* __restrict__ hist, unsigned char* __restrict__ partial) {
  __shared__ unsigned lh[NHOT_H];
  int tid = threadIdx.x;
  int lane = tid & 63;
  for (unsigned i = tid; i < NHOT_H; i += 1024) lh[i] = 0u;
  __syncthreads();
  // 8,388,608 float4 total; 32768 per block; 32 iters of 1024 threads
  const float4* p = (const float4*)score + (size_t)blockIdx.x * 32768;
  #pragma unroll 2
  for (int it = 0; it < 32; ++it) {
    float4 v = p[it * 1024 + tid];
    float vv[4] = {v.x, v.y, v.z, v.w};
    // ---- rare fp64 fixup (wave-cooperative, no global atomics) ----
    bool anyf = (fabsf(vv[0]) < FIX_TH) | (fabsf(vv[1]) < FIX_TH) |
                (fabsf(vv[2]) < FIX_TH) | (fabsf(vv[3]) < FIX_TH);
    unsigned long long am = __ballot(anyf);
    while (am) {
      int src = (int)(__ffsll((long long)am) - 1);
      am &= am - 1;
      unsigned base4 = (unsigned)(blockIdx.x * 32768u + (unsigned)(it * 1024 + tid));
      unsigned b4 = __shfl(base4, src);
      #pragma unroll
      for (int c = 0; c < 4; ++c) {
        float sc = __shfl(vv[c], src);
        if (fabsf(sc) < FIX_TH) {
          unsigned flat = b4 * 4u + (unsigned)c;
          unsigned bh = flat >> 20, i = (flat >> 10) & 1023u, j = flat & 1023u;
          double qd = (double)Q[((size_t)bh * S_LEN + i) * D_DIM + lane];
          double kd = (double)K[((size_t)bh * S_LEN + j) * D_DIM + lane];
          double pd = qd * kd;
          #pragma unroll
          for (int off = 32; off; off >>= 1) pd += __shfl_down(pd, off);
          float corr = 0.f;
          if (lane == 0)
            corr = (float)(pd * qinvD[(size_t)bh * S_LEN + i] * kinvD[(size_t)bh * S_LEN + j]);
          corr = __shfl(corr, 0);
          if (lane == src) {
            vv[c] = corr;
            score[(size_t)flat] = corr;
          }
        }
      }
    }
    // ---- binning ----
    #pragma unroll
    for (int c = 0; c < 4; ++c) {
      unsigned b = __float_as_uint(fabsf(vv[c])) >> KSHIFT;
      if (b >= NBINS) b = NBINS - 1u;
      if (b >= HIST_LO) atomicAdd(&lh[b - HIST_LO], 1u);
      else              atomicAdd(&hist[b], 1u);     // rare (~1.6e-3 of values)
    }
  }
  __syncthreads();
  unsigned char* dst = partial + (size_t)blockIdx.x * NHOT_H;
  for (unsigned i = tid; i < NHOT_H; i += 1024) dst[i] = (unsigned char)lh[i];
}

// ---------------- reduce u8 partial histograms into hist hot range ----------------
__global__ __launch_bounds__(256) void hreduce_kernel(
    const unsigned char* __restrict__ partial, unsigned* __restrict__ hist) {
  unsigned bin = blockIdx.x * 256 + threadIdx.x;   // 48 blocks * 256 = 12288
  unsigned s = 0;
  #pragma unroll 8
  for (int b = 0; b < HBLK; ++b) s += (unsigned)partial[(size_t)b * NHOT_H + bin];
  hist[HIST_LO + bin] = s;
}

// ---------------- V (fp32 [j][d]) -> Vt (fp16 [d][j]) ----------------
__global__ __launch_bounds__(256) void vt_kernel(
    const float* __restrict__ V, _Float16* __restrict__ Vt) {
  __shared__ _Float16 T[64][72];
  int bh = blockIdx.y, j0 = blockIdx.x * 64, tid = threadIdx.x;
  const float* Vb = V + ((size_t)bh * S_LEN + j0) * D_DIM;
  #pragma unroll
  for (int l = 0; l < 4; ++l) {
    int idx = l * 256 + tid;
    int jr = idx >> 4, d4 = idx & 15;
    float4 v = ((const float4*)Vb)[idx];
    T[d4*4+0][jr] = (_Float16)v.x;
    T[d4*4+1][jr] = (_Float16)v.y;
    T[d4*4+2][jr] = (_Float16)v.z;
    T[d4*4+3][jr] = (_Float16)v.w;
  }
  __syncthreads();
  _Float16* Ob = Vt + (size_t)bh * D_DIM * S_LEN + j0;
  #pragma unroll
  for (int l = 0; l < 2; ++l) {
    int idx = l * 256 + tid;
    int d = idx >> 3, jc = idx & 7;
    uint4 val = *(const uint4*)&T[d][jc*8];
    *(uint4*)(Ob + (size_t)d * S_LEN + jc*8) = val;
  }
}

// ---------------- histogram exclusive scan (3 stages), chunk=512 ----------------
__global__ __launch_bounds__(256) void scan1_kernel(const unsigned* __restrict__ hist,
                                                    unsigned* __restrict__ csum) {
  __shared__ unsigned sd[256];
  int c = blockIdx.x, t = threadIdx.x;
  const unsigned* p = hist + (size_t)c * 512;
  sd[t] = p[t] + p[t + 256];
  __syncthreads();
  for (int off = 128; off; off >>= 1) {
    if (t < off) sd[t] += sd[t + off];
    __syncthreads();
  }
  if (t == 0) csum[c] = sd[0];
}

__global__ __launch_bounds__(256) void scan2_kernel(unsigned* __restrict__ csum) {
  __shared__ unsigned d[256];
  int t = threadIdx.x;
  unsigned v = (t < NCHUNK) ? csum[t] : 0u;
  d[t] = v; __syncthreads();
  for (int off = 1; off < 256; off <<= 1) {
    unsigned x = (t >= off) ? d[t - off] : 0u;
    __syncthreads();
    d[t] += x;
    __syncthreads();
  }
  if (t < NCHUNK) csum[t] = d[t] - v;   // exclusive
}

// scan3: per-bin midrank -> tTab16[b] = fp16(-log(prob(midrank)))
__global__ __launch_bounds__(256) void scan3_kernel(const unsigned* __restrict__ hist,
                                                    const unsigned* __restrict__ csum,
                                                    _Float16* __restrict__ tTab16) {
  __shared__ unsigned ts[256];
  int c = blockIdx.x, t = threadIdx.x;
  const unsigned* p = hist + (size_t)c * 512 + t * 2;
  unsigned l0 = p[0], l1 = p[1];
  unsigned s = l0 + l1;
  ts[t] = s; __syncthreads();
  for (int off = 1; off < 256; off <<= 1) {
    unsigned x = (t >= off) ? ts[t - off] : 0u;
    __syncthreads();
    ts[t] += x;
    __syncthreads();
  }
  unsigned base = csum[c] + ts[t] - s;
  int idx = c * 512 + t * 2;
  float r0 = (float)base + 0.5f * ((float)l0 - 1.0f);
  tTab16[idx]     = (_Float16)(-__logf(fmaf(r0, INV_NM1, INV_N)));
  float r1 = (float)(base + l0) + 0.5f * ((float)l1 - 1.0f);
  tTab16[idx + 1] = (_Float16)(-__logf(fmaf(r1, INV_NM1, INV_N)));
}

// ---------------- fused map + MFMA P.V + rowsum-normalized epilogue ----------------
__global__ __launch_bounds__(256) void pv_mfma_kernel(
    const float* __restrict__ score, const _Float16* __restrict__ Vt,
    const unsigned short* __restrict__ tTab16, float* __restrict__ out) {
  __shared__ unsigned short ldsT[NHOT];
  int tid = threadIdx.x;
  {
    const unsigned* gsrc = (const unsigned*)(tTab16 + HOT_LO);
    unsigned* ldst = (unsigned*)ldsT;
    #pragma unroll
    for (int i = 0; i < 28; ++i)
      ldst[i * 256 + tid] = gsrc[i * 256 + tid];
  }
  __syncthreads();

  int bh   = blockIdx.y;
  int wave = tid >> 6;
  int lane = tid & 63;
  int m    = lane & 15;
  int quad = lane >> 4;
  int i0   = blockIdx.x * 64 + wave * 16;
  const float*    Sb = score + ((size_t)bh * S_LEN + i0 + m) * S_LEN;
  const _Float16* Vb = Vt + (size_t)bh * D_DIM * S_LEN;
  floatx4 acc[4];
  #pragma unroll
  for (int n = 0; n < 4; ++n) acc[n] = (floatx4){0.f, 0.f, 0.f, 0.f};
  float rsum = 0.f;

  for (int ks = 0; ks < 32; ++ks) {
    int k0 = ks * 32 + quad * 8;
    float4 s0 = *(const float4*)(Sb + k0);
    float4 s1 = *(const float4*)(Sb + k0 + 4);
    float sv[8] = {s0.x, s0.y, s0.z, s0.w, s1.x, s1.y, s1.z, s1.w};
    union { unsigned short u[8]; half8 h; } af;
    #pragma unroll
    for (int e = 0; e < 8; ++e) {
      unsigned u = __float_as_uint(sv[e]);
      unsigned a = u & 0x7fffffffu;
      unsigned b = a >> KSHIFT;
      if (b > NBINS - 1u) b = NBINS - 1u;
      unsigned short tb;
      if (b >= HOT_LO) tb = ldsT[b - HOT_LO];
      else             tb = tTab16[b];
      if (a == 0u) tb = 0;
      af.u[e] = (unsigned short)(tb ^ ((u >> 16) & 0x8000u));
      unsigned short tabs = (unsigned short)(tb & 0x7fffu);
      _Float16 th = __builtin_bit_cast(_Float16, tabs);
      rsum += (float)th;
    }
    half8 bf[4];
    #pragma unroll
    for (int n = 0; n < 4; ++n)
      bf[n] = *(const half8*)(Vb + (size_t)(n * 16 + m) * S_LEN + k0);
    #pragma unroll
    for (int n = 0; n < 4; ++n)
      acc[n] = __builtin_amdgcn_mfma_f32_16x16x32_f16(af.h, bf[n], acc[n], 0, 0, 0);
  }

  rsum += __shfl_xor(rsum, 16);
  rsum += __shfl_xor(rsum, 32);
  float inv = 1.0f / rsum;
  #pragma unroll
  for (int r = 0; r < 4; ++r) {
    int row = quad * 4 + r;
    float invr = __shfl(inv, row);
    float* op = out + ((size_t)bh * S_LEN + i0 + row) * D_DIM + m;
    #pragma unroll
    for (int n = 0; n < 4; ++n)
      op[n * 16] = acc[n][r] * invr;
  }
}

// ---------------- launch ----------------
extern "C" void kernel_launch(void* const* d_in, const int* in_sizes, int n_in,
                              void* d_out, int out_size, void* d_ws, size_t ws_size,
                              hipStream_t stream) {
  const float* Q = (const float*)d_in[0];
  const float* K = (const float*)d_in[1];
  const float* V = (const float*)d_in[2];
  float* out = (float*)d_out;
  char* ws = (char*)d_ws;
  // Layout (max byte used < round-7-proven 142,077,952):
  //   score [0, 134217728) ; hist [134217728, 134737920)
  //   P = 134737920:
  //     partial u8 P+0 .. P+3145728            (256*12288, live hist->hreduce)
  //     qinvD P+3145728, kinvD P+3407872       (256 KB each, live norms->hist)
  //     qinvF P+3670016, kinvF P+3801088       (128 KB each, live norms->qk)
  //     Vt    P+0 .. P+4194304                 (live vt->pv; aliases partial/qinv*/kinv*, all dead)
  //     csum  P+4456448 (1016 B, scan1->scan3)
  //     tTab16 P+4457472 (260096 B, scan3->pv)
  float*         score   = (float*)(ws);
  unsigned*      hist    = (unsigned*)(ws + 134217728);
  unsigned char* partial = (unsigned char*)(ws + 134737920);
  double*        qinvD   = (double*)(ws + 137883648);
  double*        kinvD   = (double*)(ws + 138145792);
  float*         qinvF   = (float*)(ws + 138407936);
  float*         kinvF   = (float*)(ws + 138539008);
  _Float16*      Vt      = (_Float16*)(ws + 134737920);
  unsigned*      csum    = (unsigned*)(ws + 139194368);
  _Float16*      tTab16  = (_Float16*)(ws + 139195392);

  hipMemsetAsync(hist, 0, NBINS * sizeof(unsigned), stream);
  norms_kernel<<<(2 * BH * S_LEN) / 4, 256, 0, stream>>>(Q, K, qinvD, kinvD, qinvF, kinvF);
  qk_mfma_kernel<<<dim3(16, 16, BH), 256, 0, stream>>>(Q, K, qinvF, kinvF, score);
  hist_kernel<<<HBLK, 1024, 0, stream>>>(score, Q, K, qinvD, kinvD, hist, partial);
  hreduce_kernel<<<NHOT_H / 256, 256, 0, stream>>>(partial, hist);
  vt_kernel<<<dim3(16, BH), 256, 0, stream>>>(V, Vt);
  scan1_kernel<<<NCHUNK, 256, 0, stream>>>(hist, csum);
  scan2_kernel<<<1, 256, 0, stream>>>(csum);
  scan3_kernel<<<NCHUNK, 256, 0, stream>>>(hist, csum, tTab16);
  pv_mfma_kernel<<<dim3(16, BH), 256, 0, stream>>>(
      score, Vt, (const unsigned short*)tTab16, out);
}